// Round 20
// baseline (10010.773 us; speedup 1.0000x reference)
//
#include <hip/hip_runtime.h>
#include <hip/hip_bf16.h>

#define T_LEN 2048
#define N_IN 256
#define N_H 512
#define N_B 64

typedef float f32x4 __attribute__((ext_vector_type(4)));
typedef __bf16 bf16x8 __attribute__((ext_vector_type(8)));

__device__ __forceinline__ unsigned short f2bf(float f) {
  union { float f; unsigned int i; } x; x.f = f;
  unsigned int r = x.i + 0x7fffu + ((x.i >> 16) & 1u);  // RNE
  return (unsigned short)(r >> 16);
}
__device__ __forceinline__ float sigm(float x) { return 1.0f / (1.0f + __expf(-x)); }
__device__ __forceinline__ float tanh_(float x) {
  float a = fabsf(x);
  float e = __expf(2.0f * a);
  float r = 1.0f - 2.0f / (e + 1.0f);
  return copysignf(r, x);
}
// convert 8 consecutive f32 -> bf16x8 (RNE)
__device__ __forceinline__ bf16x8 cvt8(const float* __restrict__ p) {
  f32x4 a = *(const f32x4*)(const void*)p;
  f32x4 b = *(const f32x4*)(const void*)(p + 4);
  union { bf16x8 v; unsigned short u[8]; } r;
  #pragma unroll
  for (int j = 0; j < 4; ++j) { r.u[j] = f2bf(a[j]); r.u[j + 4] = f2bf(b[j]); }
  return r.v;
}

// ws layout: hbuf u16 only (NO FLAGS — tags in the data are the sole sync):
//   [group 4][buf 4][member 8][wave 4][brow 16][hcol 16]
// group stride 32768 u16, buf stride 8192 u16. Linear addresses identical to
// r17's layout: reader u64 idx = kk*128 + roff64, writer u64 idx = m*256 + tid.
// Even-hcol u16s carry tag in bf16 LSB; h_t in buf t&3 with tag tau=(t>>2)&1.
// Init: buf 0 = 0x0000 (real h0, tag 0); bufs 1..3 = 0x0001 (invalid 1st cycle).
__global__ void lstm_init(int* __restrict__ ws) {
  int i = blockIdx.x * 256 + threadIdx.x;  // grid 256 -> 65536 ints = 256 KB
  ws[i] = ((i & 16383) < 4096) ? 0 : 0x00010001;
}

// 32 WGs x 256 threads (4 waves). Group g = bid&3 owns batch rows 16g..16g+15;
// member m = bid>>2 (0..7) owns hidden cols 64m..64m+63; wave w owns 16 of them.
// WEIGHTS LIVE IN REGISTERS (288 VGPR/lane): zero LDS reads, zero bank conflicts,
// zero barriers, zero flags. Tag-validated loads are the only synchronization.
__global__ __launch_bounds__(256, 1) void lstm_persist(
    const float* __restrict__ X,     // [64, 2048, 256] f32
    const float* __restrict__ HID,   // [1, 512] f32 (passthrough)
    const float* __restrict__ Wi, const float* __restrict__ bi,
    const float* __restrict__ Wg, const float* __restrict__ bg,
    const float* __restrict__ Wo, const float* __restrict__ bo,
    const float* __restrict__ Wout, const float* __restrict__ bout,
    float* __restrict__ out,                  // f32: [64*256] + [512]
    unsigned short* __restrict__ hbuf)
{
  __shared__ unsigned short ldsh[4 * 384];  // per-wave [16 brow][24 pad] u16
  const int tid = threadIdx.x;
  const int b = blockIdx.x;
  const int g = b & 3;
  const int m = b >> 2;
  const int lane = tid & 63;
  const int wave = tid >> 6;
  const int q = lane >> 4;
  const int c = lane & 15;
  const int colW = m * 64 + wave * 16 + c;  // this lane's hidden column

  if (b == 0) {
    for (int i = tid; i < N_H; i += 256) out[N_B * N_IN + i] = HID[i];
  }

  // ---- stage this lane's weight fragments into REGISTERS ----
  // w[gg][kt] elem j = W_gg[kt*32 + q*8 + j][colW]; kt 0..7 = x-part, 8..23 = h-part.
  bf16x8 w[3][24];
  #pragma unroll
  for (int gg = 0; gg < 3; ++gg) {
    const float* W = (gg == 0) ? Wi : ((gg == 1) ? Wg : Wo);
    #pragma unroll
    for (int kt = 0; kt < 24; ++kt) {
      union { bf16x8 v; unsigned short u[8]; } t;
      #pragma unroll
      for (int j = 0; j < 8; ++j)
        t.u[j] = f2bf(W[(size_t)(kt * 32 + q * 8 + j) * N_H + colW]);
      w[gg][kt] = t.v;
    }
  }

  const float Bi = bi[colW];
  const float Bg = bg[colW];
  const float Bo = bo[colW];

  const float* xrow = X + (size_t)(g * 16 + c) * (T_LEN * N_IN);  // A-row = group row c

  unsigned short* gh0 = hbuf + g * 32768;                  // group base (u16)
  const int roff64 = (q >> 1) * 64 + c * 4 + (q & 1) * 2;  // reader u64 idx in buf
  const int swr = wave * 384;
  const int srb = wave * 384 + (lane >> 2) * 24 + (lane & 3) * 4;
  const unsigned long long TAGM = 0x0000000100000001ull;   // LSB of each dword

  #pragma unroll 1
  for (int t = 0; t < T_LEN; ++t) {
    // ---- (a) x-part GEMM (B from registers; also the phase-alignment delay) ----
    f32x4 ai = {0.f, 0.f, 0.f, 0.f};
    f32x4 ag = {0.f, 0.f, 0.f, 0.f};
    f32x4 ao = {0.f, 0.f, 0.f, 0.f};
    const float* xp = xrow + (size_t)t * N_IN + q * 8;
    #pragma unroll
    for (int kk = 0; kk < 8; ++kk) {
      bf16x8 a = cvt8(xp + kk * 32);
      ai = __builtin_amdgcn_mfma_f32_16x16x32_bf16(a, w[0][kk], ai, 0, 0, 0);
      ag = __builtin_amdgcn_mfma_f32_16x16x32_bf16(a, w[1][kk], ag, 0, 0, 0);
      ao = __builtin_amdgcn_mfma_f32_16x16x32_bf16(a, w[2][kk], ao, 0, 0, 0);
    }

    // ---- (b) tag-validated h_t loads from buf t&3 (the ONLY synchronization) ----
    const unsigned long long* hb64 =
        (const unsigned long long*)(gh0 + (size_t)(t & 3) * 8192);
    unsigned long long hreg[32];
    {
      const unsigned long long want = ((t >> 2) & 1) ? TAGM : 0ull;
      for (;;) {
        #pragma unroll
        for (int kk = 0; kk < 16; ++kk) {
          hreg[2 * kk]     = __hip_atomic_load(hb64 + kk * 128 + roff64,
                                               __ATOMIC_RELAXED, __HIP_MEMORY_SCOPE_AGENT);
          hreg[2 * kk + 1] = __hip_atomic_load(hb64 + kk * 128 + roff64 + 1,
                                               __ATOMIC_RELAXED, __HIP_MEMORY_SCOPE_AGENT);
        }
        bool ok = true;
        #pragma unroll
        for (int i = 0; i < 32; ++i) ok &= ((hreg[i] & TAGM) == want);
        if (__all(ok)) break;
      }
    }

    // ---- (c) h-part GEMM (B from registers — no ds_read in the chain) ----
    #pragma unroll
    for (int kk = 0; kk < 16; ++kk) {
      union { unsigned long long u[2]; bf16x8 v; } a;
      a.u[0] = hreg[2 * kk]; a.u[1] = hreg[2 * kk + 1];
      ai = __builtin_amdgcn_mfma_f32_16x16x32_bf16(a.v, w[0][kk + 8], ai, 0, 0, 0);
      ag = __builtin_amdgcn_mfma_f32_16x16x32_bf16(a.v, w[1][kk + 8], ag, 0, 0, 0);
      ao = __builtin_amdgcn_mfma_f32_16x16x32_bf16(a.v, w[2][kk + 8], ao, 0, 0, 0);
    }

    // ---- (d) nonlinearity (tag even cols) -> wave-private scratch -> u64 store ----
    // Write-safety (no flags): validating h_t proves every wave issued its h_t
    // store => finished its t-1 reads => a fortiori its t-3 reads of buf (t+1)&3.
    const unsigned short tau1 = (unsigned short)(((t + 1) >> 2) & 1);
    #pragma unroll
    for (int j = 0; j < 4; ++j) {
      float iv = sigm(ai[j] + Bi);
      float gv = tanh_(ag[j] + Bg);
      float ov = sigm(ao[j] + Bo);
      float h = ov * tanh_(iv * gv);
      unsigned short hv = f2bf(h);
      if ((c & 1) == 0) hv = (unsigned short)((hv & 0xFFFEu) | tau1);  // step tag
      ldsh[swr + (q * 4 + j) * 24 + c] = hv;  // D: col=lane&15, row=q*4+j (m89)
    }
    // ordering fix (r14 lesson): fence compiler + wait own LDS writes
    asm volatile("s_waitcnt lgkmcnt(0)" ::: "memory");
    {
      unsigned long long v64;
      __builtin_memcpy(&v64, (const void*)(ldsh + srb), 8);
      unsigned long long* hn =
          (unsigned long long*)(gh0 + (size_t)((t + 1) & 3) * 8192) + m * 256 + tid;
      __hip_atomic_store(hn, v64, __ATOMIC_RELAXED, __HIP_MEMORY_SCOPE_AGENT);
    }
  }

  // ---- epilogue: out = h_T @ W_out + b_out ; h_T in buf 2048&3 = 0, tag 0 ----
  // Members 0..3 cover the 256 output cols (64 each; wave covers 16).
  if (m < 4) {
    const unsigned long long* hb64 = (const unsigned long long*)gh0;
    unsigned long long he[32];
    for (;;) {
      #pragma unroll
      for (int kk = 0; kk < 16; ++kk) {
        he[2 * kk]     = __hip_atomic_load(hb64 + kk * 128 + roff64,
                                           __ATOMIC_RELAXED, __HIP_MEMORY_SCOPE_AGENT);
        he[2 * kk + 1] = __hip_atomic_load(hb64 + kk * 128 + roff64 + 1,
                                           __ATOMIC_RELAXED, __HIP_MEMORY_SCOPE_AGENT);
      }
      bool ok = true;
      #pragma unroll
      for (int i = 0; i < 32; ++i) ok &= ((he[i] & TAGM) == 0ull);
      if (__all(ok)) break;
    }
    const int oc = m * 64 + wave * 16 + c;  // output column
    f32x4 acc = {0.f, 0.f, 0.f, 0.f};
    #pragma unroll 4
    for (int kk = 0; kk < 16; ++kk) {
      union { unsigned long long u[2]; bf16x8 v; } a;
      a.u[0] = he[2 * kk]; a.u[1] = he[2 * kk + 1];
      union { bf16x8 v; unsigned short u[8]; } bb;
      #pragma unroll
      for (int j = 0; j < 8; ++j)
        bb.u[j] = f2bf(Wout[(size_t)(kk * 32 + q * 8 + j) * N_IN + oc]);
      acc = __builtin_amdgcn_mfma_f32_16x16x32_bf16(a.v, bb.v, acc, 0, 0, 0);
    }
    const float Bb = bout[oc];
    #pragma unroll
    for (int j = 0; j < 4; ++j) {
      int row = q * 4 + j;  // group row
      out[(g * 16 + row) * N_IN + oc] = acc[j] + Bb;  // f32 store
    }
  }
}

extern "C" void kernel_launch(void* const* d_in, const int* in_sizes, int n_in,
                              void* d_out, int out_size, void* d_ws, size_t ws_size,
                              hipStream_t stream) {
  const float* X    = (const float*)d_in[0];
  const float* HID  = (const float*)d_in[1];
  const float* Wi   = (const float*)d_in[2];
  const float* bi   = (const float*)d_in[3];
  const float* Wg   = (const float*)d_in[4];
  const float* bg   = (const float*)d_in[5];
  const float* Wo   = (const float*)d_in[6];
  const float* bo   = (const float*)d_in[7];
  const float* Wout = (const float*)d_in[8];
  const float* bout = (const float*)d_in[9];

  unsigned short* hbuf = (unsigned short*)d_ws;  // 256 KB

  lstm_init<<<dim3(256), dim3(256), 0, stream>>>((int*)d_ws);
  lstm_persist<<<dim3(32), dim3(256), 0, stream>>>(
      X, HID, Wi, bi, Wg, bg, Wo, bo, Wout, bout,
      (float*)d_out, hbuf);
}

// Round 21
// 8759.283 us; speedup vs baseline: 1.1429x; 1.1429x over previous
//
#include <hip/hip_runtime.h>
#include <hip/hip_bf16.h>

#define T_LEN 2048
#define N_IN 256
#define N_H 512
#define N_B 64

typedef float f32x4 __attribute__((ext_vector_type(4)));
typedef __bf16 bf16x8 __attribute__((ext_vector_type(8)));

__device__ __forceinline__ unsigned short f2bf(float f) {
  union { float f; unsigned int i; } x; x.f = f;
  unsigned int r = x.i + 0x7fffu + ((x.i >> 16) & 1u);  // RNE
  return (unsigned short)(r >> 16);
}
__device__ __forceinline__ float sigm(float x) { return 1.0f / (1.0f + __expf(-x)); }
__device__ __forceinline__ float tanh_(float x) {
  float a = fabsf(x);
  float e = __expf(2.0f * a);
  float r = 1.0f - 2.0f / (e + 1.0f);
  return copysignf(r, x);
}
// convert 8 consecutive f32 -> bf16x8 (RNE)
__device__ __forceinline__ bf16x8 cvt8(const float* __restrict__ p) {
  f32x4 a = *(const f32x4*)(const void*)p;
  f32x4 b = *(const f32x4*)(const void*)(p + 4);
  union { bf16x8 v; unsigned short u[8]; } r;
  #pragma unroll
  for (int j = 0; j < 4; ++j) { r.u[j] = f2bf(a[j]); r.u[j + 4] = f2bf(b[j]); }
  return r.v;
}

// ws layout: hbuf u16 only (NO FLAGS — tags inside the data are the sole sync):
//   [group 4][buf 4][slice 16][whalf 2][brow 16][hcol 16]
// group stride 32768 u16, buf stride 8192 u16. Even-hcol u16s carry tag in bf16
// LSB; h_t lives in buf t&3 with tag tau(t) = (t>>2)&1. Init: buf 0 = 0x0000
// (real h0, tag 0 valid for t=0); bufs 1..3 = 0x0001 (tag 1, invalid first cycle).
__global__ void lstm_init(int* __restrict__ ws) {
  int i = blockIdx.x * 256 + threadIdx.x;  // grid 256 -> 65536 ints = 256 KB
  ws[i] = ((i & 16383) < 4096) ? 0 : 0x00010001;
}

// 64 WGs x 128 threads. Group g = bid&3 owns batch rows 16g..16g+15 (independent
// recurrence). Member m = bid>>2 owns hidden cols 32m..32m+31; wave w owns 16.
// Zero barriers/flags in main loop. NEW vs r17: software-pipelined x-GEMM —
// the x-gates for step t+1 are computed INSIDE step t's h-load RT shadow.
__global__ __launch_bounds__(128, 1) void lstm_persist(
    const float* __restrict__ X,     // [64, 2048, 256] f32
    const float* __restrict__ HID,   // [1, 512] f32 (passthrough)
    const float* __restrict__ Wi, const float* __restrict__ bi,
    const float* __restrict__ Wg, const float* __restrict__ bg,
    const float* __restrict__ Wo, const float* __restrict__ bo,
    const float* __restrict__ Wout, const float* __restrict__ bout,
    float* __restrict__ out,                  // f32: [64*256] + [512]
    unsigned short* __restrict__ hbuf)
{
  extern __shared__ unsigned short ldsw[];  // 96*768 swizzled weights + 768 u16 scratch
  unsigned short* ldsh = ldsw + 96 * 768;   // per-wave [16 brow][24 pad] u16
  const int tid = threadIdx.x;
  const int b = blockIdx.x;
  const int g = b & 3;
  const int m = b >> 2;
  const int lane = tid & 63;
  const int wave = tid >> 6;
  const int q = lane >> 4;
  const int c = lane & 15;
  const int jb = m * 32;
  const int wcol = wave * 16;

  if (b == 0) {
    for (int i = tid; i < N_H; i += 128) out[N_B * N_IN + i] = HID[i];
  }

  // ---- stage weight slice into LDS (f32 -> bf16), transposed + swizzled ----
  for (int idx = tid; idx < 96 * 768; idx += 128) {
    int k = idx / 96, r = idx - k * 96;
    int g3 = r >> 5, cc = r & 31;
    const float* W = (g3 == 0) ? Wi : ((g3 == 1) ? Wg : Wo);
    unsigned short v = f2bf(W[k * N_H + jb + cc]);
    int byte = (r * 1536 + k * 2) ^ ((r & 7) << 4);  // XOR swizzle (G4)
    *(unsigned short*)((char*)ldsw + byte) = v;
  }
  __syncthreads();  // only block-wide barrier (weights read-only afterwards)

  auto ldb = [&](int gg, int kt) -> bf16x8 {
    int r = gg * 32 + wcol + c;
    int byte = (r * 1536 + kt * 64 + q * 16) ^ ((r & 7) << 4);
    return *(const bf16x8*)((const char*)ldsw + byte);
  };

  const float Bi = bi[jb + wcol + c];
  const float Bg = bg[jb + wcol + c];
  const float Bo = bo[jb + wcol + c];

  const float* xrow = X + (size_t)(g * 16 + c) * (T_LEN * N_IN);

  unsigned short* gh0 = hbuf + g * 32768;                  // group base (u16)
  const int roff64 = (q >> 1) * 64 + c * 4 + (q & 1) * 2;  // reader u64 idx in buf
  const int swr = wave * 384;
  const int srb = wave * 384 + (lane >> 2) * 24 + (lane & 3) * 4;
  const unsigned long long TAGM = 0x0000000100000001ull;   // LSB of each dword

  // ---- pipelined x-gate accumulators: (xi,xg,xo) hold x-GEMM for CURRENT step ----
  f32x4 xi = {0.f, 0.f, 0.f, 0.f};
  f32x4 xg = {0.f, 0.f, 0.f, 0.f};
  f32x4 xo = {0.f, 0.f, 0.f, 0.f};
  {
    const float* xp = xrow + q * 8;  // t = 0
    #pragma unroll
    for (int kk = 0; kk < 8; ++kk) {
      bf16x8 a = cvt8(xp + kk * 32);
      xi = __builtin_amdgcn_mfma_f32_16x16x32_bf16(a, ldb(0, kk), xi, 0, 0, 0);
      xg = __builtin_amdgcn_mfma_f32_16x16x32_bf16(a, ldb(1, kk), xg, 0, 0, 0);
      xo = __builtin_amdgcn_mfma_f32_16x16x32_bf16(a, ldb(2, kk), xo, 0, 0, 0);
    }
  }

  #pragma unroll 1
  for (int t = 0; t < T_LEN; ++t) {
    // ---- (a) issue h_t loads FIRST (RT overlaps the next block) ----
    const unsigned long long* hb64 =
        (const unsigned long long*)(gh0 + (size_t)(t & 3) * 8192);
    unsigned long long hreg[32];
    #pragma unroll
    for (int kk = 0; kk < 16; ++kk) {
      hreg[2 * kk]     = __hip_atomic_load(hb64 + kk * 128 + roff64,
                                           __ATOMIC_RELAXED, __HIP_MEMORY_SCOPE_AGENT);
      hreg[2 * kk + 1] = __hip_atomic_load(hb64 + kk * 128 + roff64 + 1,
                                           __ATOMIC_RELAXED, __HIP_MEMORY_SCOPE_AGENT);
    }

    // ---- (b) x-GEMM for step t+1 inside the load shadow (independent of h_t) ----
    f32x4 ni = {0.f, 0.f, 0.f, 0.f};
    f32x4 ng = {0.f, 0.f, 0.f, 0.f};
    f32x4 no = {0.f, 0.f, 0.f, 0.f};
    {
      int tn = (t + 1 < T_LEN) ? t + 1 : t;  // clamped; last lookahead unused
      const float* xp = xrow + (size_t)tn * N_IN + q * 8;
      #pragma unroll
      for (int kk = 0; kk < 8; ++kk) {
        bf16x8 a = cvt8(xp + kk * 32);
        ni = __builtin_amdgcn_mfma_f32_16x16x32_bf16(a, ldb(0, kk), ni, 0, 0, 0);
        ng = __builtin_amdgcn_mfma_f32_16x16x32_bf16(a, ldb(1, kk), ng, 0, 0, 0);
        no = __builtin_amdgcn_mfma_f32_16x16x32_bf16(a, ldb(2, kk), no, 0, 0, 0);
      }
    }

    // ---- (c) validate tags (first use of hreg -> vmcnt wait lands here) ----
    {
      const unsigned long long want = ((t >> 2) & 1) ? TAGM : 0ull;
      for (;;) {
        bool ok = true;
        #pragma unroll
        for (int i = 0; i < 32; ++i) ok &= ((hreg[i] & TAGM) == want);
        if (__all(ok)) break;
        #pragma unroll
        for (int kk = 0; kk < 16; ++kk) {
          hreg[2 * kk]     = __hip_atomic_load(hb64 + kk * 128 + roff64,
                                               __ATOMIC_RELAXED, __HIP_MEMORY_SCOPE_AGENT);
          hreg[2 * kk + 1] = __hip_atomic_load(hb64 + kk * 128 + roff64 + 1,
                                               __ATOMIC_RELAXED, __HIP_MEMORY_SCOPE_AGENT);
        }
      }
    }

    // ---- (d) h-part GEMM accumulates onto the CURRENT step's x-gates ----
    #pragma unroll
    for (int kk = 0; kk < 16; ++kk) {
      union { unsigned long long u[2]; bf16x8 v; } a;
      a.u[0] = hreg[2 * kk]; a.u[1] = hreg[2 * kk + 1];
      xi = __builtin_amdgcn_mfma_f32_16x16x32_bf16(a.v, ldb(0, kk + 8), xi, 0, 0, 0);
      xg = __builtin_amdgcn_mfma_f32_16x16x32_bf16(a.v, ldb(1, kk + 8), xg, 0, 0, 0);
      xo = __builtin_amdgcn_mfma_f32_16x16x32_bf16(a.v, ldb(2, kk + 8), xo, 0, 0, 0);
    }

    // ---- (e) nonlinearity (tag even cols) -> scratch -> u64 store to buf (t+1)&3 ----
    // Write-safety (no flags): validating h_t proves every wave issued its h_t
    // store => finished its t-1 reads => a fortiori its t-3 reads of buf (t+1)&3.
    const unsigned short tau1 = (unsigned short)(((t + 1) >> 2) & 1);
    #pragma unroll
    for (int j = 0; j < 4; ++j) {
      float iv = sigm(xi[j] + Bi);
      float gv = tanh_(xg[j] + Bg);
      float ov = sigm(xo[j] + Bo);
      float h = ov * tanh_(iv * gv);
      unsigned short hv = f2bf(h);
      if ((c & 1) == 0) hv = (unsigned short)((hv & 0xFFFEu) | tau1);  // step tag
      ldsh[swr + (q * 4 + j) * 24 + c] = hv;  // D: col=lane&15, row=q*4+j (m89)
    }
    // ordering fix (r14 lesson): fence compiler + wait own LDS writes
    asm volatile("s_waitcnt lgkmcnt(0)" ::: "memory");
    {
      unsigned long long v64;
      __builtin_memcpy(&v64, (const void*)(ldsh + srb), 8);
      unsigned long long* hn =
          (unsigned long long*)(gh0 + (size_t)((t + 1) & 3) * 8192) + m * 128 + tid;
      __hip_atomic_store(hn, v64, __ATOMIC_RELAXED, __HIP_MEMORY_SCOPE_AGENT);
    }

    // ---- (f) rotate the pipelined x-gates ----
    xi = ni; xg = ng; xo = no;
  }

  // ---- epilogue: out = h_T @ W_out + b_out ; h_T in buf 2048&3 = 0, tag 0 ----
  if (wave == 0) {
    const unsigned long long* hb64 = (const unsigned long long*)gh0;
    unsigned long long he[32];
    for (;;) {
      #pragma unroll
      for (int kk = 0; kk < 16; ++kk) {
        he[2 * kk]     = __hip_atomic_load(hb64 + kk * 128 + roff64,
                                           __ATOMIC_RELAXED, __HIP_MEMORY_SCOPE_AGENT);
        he[2 * kk + 1] = __hip_atomic_load(hb64 + kk * 128 + roff64 + 1,
                                           __ATOMIC_RELAXED, __HIP_MEMORY_SCOPE_AGENT);
      }
      bool ok = true;
      #pragma unroll
      for (int i = 0; i < 32; ++i) ok &= ((he[i] & TAGM) == 0ull);
      if (__all(ok)) break;
    }
    f32x4 acc = {0.f, 0.f, 0.f, 0.f};
    #pragma unroll 4
    for (int kk = 0; kk < 16; ++kk) {
      union { unsigned long long u[2]; bf16x8 v; } a;
      a.u[0] = he[2 * kk]; a.u[1] = he[2 * kk + 1];
      union { bf16x8 v; unsigned short u[8]; } bb;
      #pragma unroll
      for (int j = 0; j < 8; ++j)
        bb.u[j] = f2bf(Wout[(size_t)(kk * 32 + q * 8 + j) * N_IN + m * 16 + c]);
      acc = __builtin_amdgcn_mfma_f32_16x16x32_bf16(a.v, bb.v, acc, 0, 0, 0);
    }
    const float Bb = bout[m * 16 + c];
    #pragma unroll
    for (int j = 0; j < 4; ++j) {
      int row = q * 4 + j;
      out[(g * 16 + row) * N_IN + m * 16 + c] = acc[j] + Bb;
    }
  }
}

extern "C" void kernel_launch(void* const* d_in, const int* in_sizes, int n_in,
                              void* d_out, int out_size, void* d_ws, size_t ws_size,
                              hipStream_t stream) {
  const float* X    = (const float*)d_in[0];
  const float* HID  = (const float*)d_in[1];
  const float* Wi   = (const float*)d_in[2];
  const float* bi   = (const float*)d_in[3];
  const float* Wg   = (const float*)d_in[4];
  const float* bg   = (const float*)d_in[5];
  const float* Wo   = (const float*)d_in[6];
  const float* bo   = (const float*)d_in[7];
  const float* Wout = (const float*)d_in[8];
  const float* bout = (const float*)d_in[9];

  unsigned short* hbuf = (unsigned short*)d_ws;  // 256 KB

  lstm_init<<<dim3(256), dim3(256), 0, stream>>>((int*)d_ws);
  lstm_persist<<<dim3(64), dim3(128), 96 * 768 * 2 + 1536, stream>>>(
      X, HID, Wi, bi, Wg, bg, Wo, bo, Wout, bout,
      (float*)d_out, hbuf);
}

// Round 22
// 6943.040 us; speedup vs baseline: 1.4418x; 1.2616x over previous
//
#include <hip/hip_runtime.h>
#include <hip/hip_bf16.h>

#define T_LEN 2048
#define N_IN 256
#define N_H 512
#define N_B 64

typedef float f32x4 __attribute__((ext_vector_type(4)));
typedef __bf16 bf16x8 __attribute__((ext_vector_type(8)));

__device__ __forceinline__ unsigned short f2bf(float f) {
  union { float f; unsigned int i; } x; x.f = f;
  unsigned int r = x.i + 0x7fffu + ((x.i >> 16) & 1u);  // RNE
  return (unsigned short)(r >> 16);
}
__device__ __forceinline__ float sigm(float x) { return 1.0f / (1.0f + __expf(-x)); }
__device__ __forceinline__ float tanh_(float x) {
  float a = fabsf(x);
  float e = __expf(2.0f * a);
  float r = 1.0f - 2.0f / (e + 1.0f);
  return copysignf(r, x);
}
// convert 8 consecutive f32 -> bf16x8 (RNE)
__device__ __forceinline__ bf16x8 cvt8(const float* __restrict__ p) {
  f32x4 a = *(const f32x4*)(const void*)p;
  f32x4 b = *(const f32x4*)(const void*)(p + 4);
  union { bf16x8 v; unsigned short u[8]; } r;
  #pragma unroll
  for (int j = 0; j < 4; ++j) { r.u[j] = f2bf(a[j]); r.u[j + 4] = f2bf(b[j]); }
  return r.v;
}

// ws layout: hbuf u16 only (NO FLAGS — tags inside the data are the sole sync):
//   [group 4][buf 4][slice 16][whalf 2][brow 16][hcol 16]
// group stride 32768 u16, buf stride 8192 u16. Even-hcol u16s carry tag in bf16
// LSB; h_t lives in buf t&3 with tag tau(t) = (t>>2)&1. Init: buf 0 = 0x0000
// (real h0, tag 0 = valid for t=0); bufs 1..3 = 0x0001 (tag 1 = invalid first cycle).
__global__ void lstm_init(int* __restrict__ ws) {
  int i = blockIdx.x * 256 + threadIdx.x;  // grid 256 -> 65536 ints = 256 KB
  ws[i] = ((i & 16383) < 4096) ? 0 : 0x00010001;
}

// 64 WGs x 128 threads. Group g = bid&3 owns batch rows 16g..16g+15 (independent
// recurrence). Member m = bid>>2 owns hidden cols 32m..32m+31; wave w owns 16.
// Zero barriers, zero flags in the main loop: tag-validated speculative loads
// provide both data freshness AND (transitively) overwrite safety with 4 bufs.
__global__ __launch_bounds__(128, 1) void lstm_persist(
    const float* __restrict__ X,     // [64, 2048, 256] f32
    const float* __restrict__ HID,   // [1, 512] f32 (passthrough)
    const float* __restrict__ Wi, const float* __restrict__ bi,
    const float* __restrict__ Wg, const float* __restrict__ bg,
    const float* __restrict__ Wo, const float* __restrict__ bo,
    const float* __restrict__ Wout, const float* __restrict__ bout,
    float* __restrict__ out,                  // f32: [64*256] + [512]
    unsigned short* __restrict__ hbuf)
{
  extern __shared__ unsigned short ldsw[];  // 96*768 swizzled weights + 768 u16 scratch
  unsigned short* ldsh = ldsw + 96 * 768;   // per-wave [16 brow][24 pad] u16
  const int tid = threadIdx.x;
  const int b = blockIdx.x;
  const int g = b & 3;
  const int m = b >> 2;
  const int lane = tid & 63;
  const int wave = tid >> 6;
  const int q = lane >> 4;
  const int c = lane & 15;
  const int jb = m * 32;
  const int wcol = wave * 16;

  if (b == 0) {
    for (int i = tid; i < N_H; i += 128) out[N_B * N_IN + i] = HID[i];
  }

  // ---- stage weight slice into LDS (f32 -> bf16), transposed + swizzled ----
  for (int idx = tid; idx < 96 * 768; idx += 128) {
    int k = idx / 96, r = idx - k * 96;
    int g3 = r >> 5, cc = r & 31;
    const float* W = (g3 == 0) ? Wi : ((g3 == 1) ? Wg : Wo);
    unsigned short v = f2bf(W[k * N_H + jb + cc]);
    int byte = (r * 1536 + k * 2) ^ ((r & 7) << 4);  // XOR swizzle (G4)
    *(unsigned short*)((char*)ldsw + byte) = v;
  }
  __syncthreads();  // only block-wide barrier (weights read-only afterwards)

  auto ldb = [&](int gg, int kt) -> bf16x8 {
    int r = gg * 32 + wcol + c;
    int byte = (r * 1536 + kt * 64 + q * 16) ^ ((r & 7) << 4);
    return *(const bf16x8*)((const char*)ldsw + byte);
  };

  const float Bi = bi[jb + wcol + c];
  const float Bg = bg[jb + wcol + c];
  const float Bo = bo[jb + wcol + c];

  const float* xrow = X + (size_t)(g * 16 + c) * (T_LEN * N_IN);

  unsigned short* gh0 = hbuf + g * 32768;                  // group base (u16)
  const int roff64 = (q >> 1) * 64 + c * 4 + (q & 1) * 2;  // reader u64 idx in slice
  const int swr = wave * 384;
  const int srb = wave * 384 + (lane >> 2) * 24 + (lane & 3) * 4;
  const unsigned long long TAGM = 0x0000000100000001ull;   // LSB of each dword

  #pragma unroll 1
  for (int t = 0; t < T_LEN; ++t) {
    // ---- (a) x-part GEMM first (phase-aligns the h loads with store landing) ----
    f32x4 ai = {0.f, 0.f, 0.f, 0.f};
    f32x4 ag = {0.f, 0.f, 0.f, 0.f};
    f32x4 ao = {0.f, 0.f, 0.f, 0.f};
    const float* xp = xrow + (size_t)t * N_IN + q * 8;
    #pragma unroll
    for (int kk = 0; kk < 8; ++kk) {
      bf16x8 a = cvt8(xp + kk * 32);
      ai = __builtin_amdgcn_mfma_f32_16x16x32_bf16(a, ldb(0, kk), ai, 0, 0, 0);
      ag = __builtin_amdgcn_mfma_f32_16x16x32_bf16(a, ldb(1, kk), ag, 0, 0, 0);
      ao = __builtin_amdgcn_mfma_f32_16x16x32_bf16(a, ldb(2, kk), ao, 0, 0, 0);
    }

    // ---- (b) tag-validated h_t loads from buf t&3 (the ONLY synchronization) ----
    const unsigned long long* hb64 =
        (const unsigned long long*)(gh0 + (size_t)(t & 3) * 8192);
    unsigned long long hreg[32];
    {
      const unsigned long long want = ((t >> 2) & 1) ? TAGM : 0ull;
      for (;;) {
        #pragma unroll
        for (int kk = 0; kk < 16; ++kk) {
          hreg[2 * kk]     = __hip_atomic_load(hb64 + kk * 128 + roff64,
                                               __ATOMIC_RELAXED, __HIP_MEMORY_SCOPE_AGENT);
          hreg[2 * kk + 1] = __hip_atomic_load(hb64 + kk * 128 + roff64 + 1,
                                               __ATOMIC_RELAXED, __HIP_MEMORY_SCOPE_AGENT);
        }
        bool ok = true;
        #pragma unroll
        for (int i = 0; i < 32; ++i) ok &= ((hreg[i] & TAGM) == want);
        if (__all(ok)) break;
      }
    }

    // ---- (c) h-part GEMM ----
    #pragma unroll
    for (int kk = 0; kk < 16; ++kk) {
      union { unsigned long long u[2]; bf16x8 v; } a;
      a.u[0] = hreg[2 * kk]; a.u[1] = hreg[2 * kk + 1];
      ai = __builtin_amdgcn_mfma_f32_16x16x32_bf16(a.v, ldb(0, kk + 8), ai, 0, 0, 0);
      ag = __builtin_amdgcn_mfma_f32_16x16x32_bf16(a.v, ldb(1, kk + 8), ag, 0, 0, 0);
      ao = __builtin_amdgcn_mfma_f32_16x16x32_bf16(a.v, ldb(2, kk + 8), ao, 0, 0, 0);
    }

    // ---- (d) nonlinearity (tag even cols) -> scratch -> u64 store to buf (t+1)&3 ----
    // Write-safety without flags: successful validation of h_t proves every wave
    // issued its h_t store => every wave finished its step t-1 reads => a fortiori
    // finished its step t-3 reads of buf (t+1)&3. Overwrite is safe.
    const unsigned short tau1 = (unsigned short)(((t + 1) >> 2) & 1);
    #pragma unroll
    for (int j = 0; j < 4; ++j) {
      float iv = sigm(ai[j] + Bi);
      float gv = tanh_(ag[j] + Bg);
      float ov = sigm(ao[j] + Bo);
      float h = ov * tanh_(iv * gv);
      unsigned short hv = f2bf(h);
      if ((c & 1) == 0) hv = (unsigned short)((hv & 0xFFFEu) | tau1);  // step tag
      ldsh[swr + (q * 4 + j) * 24 + c] = hv;  // D: col=lane&15, row=q*4+j (m89)
    }
    // ordering fix (r14 lesson): fence compiler + wait own LDS writes
    asm volatile("s_waitcnt lgkmcnt(0)" ::: "memory");
    {
      unsigned long long v64;
      __builtin_memcpy(&v64, (const void*)(ldsh + srb), 8);
      unsigned long long* hn =
          (unsigned long long*)(gh0 + (size_t)((t + 1) & 3) * 8192) + m * 128 + tid;
      __hip_atomic_store(hn, v64, __ATOMIC_RELAXED, __HIP_MEMORY_SCOPE_AGENT);
    }
  }

  // ---- epilogue: out = h_T @ W_out + b_out ; h_T in buf 2048&3 = 0, tag 0 ----
  if (wave == 0) {
    const unsigned long long* hb64 = (const unsigned long long*)gh0;
    unsigned long long he[32];
    for (;;) {
      #pragma unroll
      for (int kk = 0; kk < 16; ++kk) {
        he[2 * kk]     = __hip_atomic_load(hb64 + kk * 128 + roff64,
                                           __ATOMIC_RELAXED, __HIP_MEMORY_SCOPE_AGENT);
        he[2 * kk + 1] = __hip_atomic_load(hb64 + kk * 128 + roff64 + 1,
                                           __ATOMIC_RELAXED, __HIP_MEMORY_SCOPE_AGENT);
      }
      bool ok = true;
      #pragma unroll
      for (int i = 0; i < 32; ++i) ok &= ((he[i] & TAGM) == 0ull);
      if (__all(ok)) break;
    }
    f32x4 acc = {0.f, 0.f, 0.f, 0.f};
    #pragma unroll 4
    for (int kk = 0; kk < 16; ++kk) {
      union { unsigned long long u[2]; bf16x8 v; } a;
      a.u[0] = he[2 * kk]; a.u[1] = he[2 * kk + 1];
      union { bf16x8 v; unsigned short u[8]; } bb;
      #pragma unroll
      for (int j = 0; j < 8; ++j)
        bb.u[j] = f2bf(Wout[(size_t)(kk * 32 + q * 8 + j) * N_IN + m * 16 + c]);
      acc = __builtin_amdgcn_mfma_f32_16x16x32_bf16(a.v, bb.v, acc, 0, 0, 0);
    }
    const float Bb = bout[m * 16 + c];
    #pragma unroll
    for (int j = 0; j < 4; ++j) {
      int row = q * 4 + j;
      out[(g * 16 + row) * N_IN + m * 16 + c] = acc[j] + Bb;
    }
  }
}

extern "C" void kernel_launch(void* const* d_in, const int* in_sizes, int n_in,
                              void* d_out, int out_size, void* d_ws, size_t ws_size,
                              hipStream_t stream) {
  const float* X    = (const float*)d_in[0];
  const float* HID  = (const float*)d_in[1];
  const float* Wi   = (const float*)d_in[2];
  const float* bi   = (const float*)d_in[3];
  const float* Wg   = (const float*)d_in[4];
  const float* bg   = (const float*)d_in[5];
  const float* Wo   = (const float*)d_in[6];
  const float* bo   = (const float*)d_in[7];
  const float* Wout = (const float*)d_in[8];
  const float* bout = (const float*)d_in[9];

  unsigned short* hbuf = (unsigned short*)d_ws;  // 256 KB

  lstm_init<<<dim3(256), dim3(256), 0, stream>>>((int*)d_ws);
  lstm_persist<<<dim3(64), dim3(128), 96 * 768 * 2 + 1536, stream>>>(
      X, HID, Wi, bi, Wg, bg, Wo, bo, Wout, bout,
      (float*)d_out, hbuf);
}